// Round 7
// baseline (839.083 us; speedup 1.0000x reference)
//
#include <hip/hip_runtime.h>

#define N_NODES 50000
#define N_EDGES 800000

#define BVALS 64                                  // nodes per bucket
#define NBUK ((N_NODES + BVALS - 1) / BVALS)      // 782
#define PAD 16                                    // ints per padded counter (64B line)
#define CHUNK 4096                                // edges per count/scatter block
#define ASTRIDE 68                                // LDS acc row stride (floats) — bank skew

// ---------------- bf16 helpers (tables stored bf16, math in fp32) ----------------

__device__ __forceinline__ float bf2f(unsigned short u) {
    return __uint_as_float(((unsigned)u) << 16);
}
__device__ __forceinline__ unsigned short f2bf(float f) {
    unsigned u = __float_as_uint(f);
    u += 0x7FFFu + ((u >> 16) & 1u);   // round-to-nearest-even
    return (unsigned short)(u >> 16);
}
__device__ __forceinline__ void stv(float* p, float v) { *p = v; }
__device__ __forceinline__ void stv(unsigned short* p, float v) { *p = f2bf(v); }

// ---------------- bucket build: count -> scan -> scatter ----------------
// Contention control: per-block LDS histograms; global counters padded 1/line.

__global__ __launch_bounds__(256) void count_kernel(
        const int* __restrict__ ei, int* __restrict__ bcnt_pad, int E) {
    __shared__ int hist[NBUK];
    int t = threadIdx.x;
    for (int h = t; h < NBUK; h += 256) hist[h] = 0;
    __syncthreads();
    int e0 = blockIdx.x * CHUNK;
    int ne = min(CHUNK, E - e0);
    for (int i = t; i < ne; i += 256)
        atomicAdd(&hist[ei[E + e0 + i] >> 6], 1);
    __syncthreads();
    for (int h = t; h < NBUK; h += 256) {
        int c = hist[h];
        if (c) atomicAdd(&bcnt_pad[h * PAD], c);
    }
}

__global__ __launch_bounds__(1024) void scan_kernel(
        const int* __restrict__ bcnt_pad, int* __restrict__ bofs,
        int* __restrict__ gcur_pad) {
    __shared__ int lds[1024];
    int t = threadIdx.x;
    int v = (t < NBUK) ? bcnt_pad[t * PAD] : 0;
    lds[t] = v;
    __syncthreads();
    for (int off = 1; off < 1024; off <<= 1) {
        int u = (t >= off) ? lds[t - off] : 0;
        __syncthreads();
        lds[t] += u;
        __syncthreads();
    }
    if (t <= NBUK) bofs[t] = lds[t] - v;          // exclusive; bofs[NBUK] = E
    if (t < NBUK) gcur_pad[t * PAD] = lds[t] - v; // scatter cursors start at bofs
}

__global__ __launch_bounds__(256) void scatter_kernel(
        const int* __restrict__ ei, int* __restrict__ gcur_pad,
        unsigned int* __restrict__ bpk, int E) {
    __shared__ unsigned int pk[CHUNK];   // 16KB
    __shared__ int hist[NBUK];           // 3.1KB
    __shared__ int lbase[NBUK];          // 3.1KB
    int t = threadIdx.x;
    for (int h = t; h < NBUK; h += 256) hist[h] = 0;
    __syncthreads();
    int e0 = blockIdx.x * CHUNK;
    int ne = min(CHUNK, E - e0);
    for (int i = t; i < ne; i += 256) {
        unsigned s = (unsigned)ei[e0 + i];
        unsigned d = (unsigned)ei[E + e0 + i];
        pk[i] = (d << 16) | s;
        atomicAdd(&hist[d >> 6], 1);
    }
    __syncthreads();
    for (int h = t; h < NBUK; h += 256) {
        int c = hist[h];
        lbase[h] = c ? atomicAdd(&gcur_pad[h * PAD], c) : 0;
        hist[h] = 0;                     // reuse as local cursor
    }
    __syncthreads();
    for (int i = t; i < ne; i += 256) {
        unsigned v = pk[i];
        int h = (v >> 16) >> 6;
        int idx = atomicAdd(&hist[h], 1);
        bpk[lbase[h] + idx] = v;
    }
}

// ---------------- fused dual GEMM: C0 = A@W0, C1 = A@W1 ----------------

template<int K, typename T0, typename T1>
__global__ __launch_bounds__(256) void gemm_dual_kernel(
        const float* __restrict__ A,
        const float* __restrict__ W0, const float* __restrict__ W1,
        T0* __restrict__ C0, T1* __restrict__ C1, int N) {
    __shared__ float a_lds[32 * K];
    int t = threadIdx.x;
    int n0 = blockIdx.x * 32;

    const int total4 = 32 * K / 4;
    for (int idx = t; idx < total4; idx += 256) {
        int f = idx * 4;
        int r = f / K, c = f % K;
        float4 v = make_float4(0.f, 0.f, 0.f, 0.f);
        if (n0 + r < N) v = *(const float4*)&A[(size_t)(n0 + r) * K + c];
        *(float4*)&a_lds[f] = v;
    }
    __syncthreads();

    int o = t & 63;
    int g = t >> 6;
    float acc0[8], acc1[8];
#pragma unroll
    for (int i = 0; i < 8; ++i) { acc0[i] = 0.f; acc1[i] = 0.f; }

#pragma unroll 2
    for (int k4 = 0; k4 < K; k4 += 4) {
        float w00 = W0[(k4 + 0) * 64 + o];
        float w01 = W0[(k4 + 1) * 64 + o];
        float w02 = W0[(k4 + 2) * 64 + o];
        float w03 = W0[(k4 + 3) * 64 + o];
        float w10 = W1[(k4 + 0) * 64 + o];
        float w11 = W1[(k4 + 1) * 64 + o];
        float w12 = W1[(k4 + 2) * 64 + o];
        float w13 = W1[(k4 + 3) * 64 + o];
#pragma unroll
        for (int i = 0; i < 8; ++i) {
            float4 a = *(const float4*)&a_lds[(g * 8 + i) * K + k4];
            acc0[i] = fmaf(a.x, w00, acc0[i]);
            acc0[i] = fmaf(a.y, w01, acc0[i]);
            acc0[i] = fmaf(a.z, w02, acc0[i]);
            acc0[i] = fmaf(a.w, w03, acc0[i]);
            acc1[i] = fmaf(a.x, w10, acc1[i]);
            acc1[i] = fmaf(a.y, w11, acc1[i]);
            acc1[i] = fmaf(a.z, w12, acc1[i]);
            acc1[i] = fmaf(a.w, w13, acc1[i]);
        }
    }
#pragma unroll
    for (int i = 0; i < 8; ++i) {
        int n = n0 + g * 8 + i;
        if (n < N) {
            stv(&C0[(size_t)n * 64 + o], acc0[i]);
            stv(&C1[(size_t)n * 64 + o], acc1[i]);
        }
    }
}

// ---------------- fused bucket-sort + mean-aggregate + bias + residual + relu ----
// One block per bucket of 64 dst nodes. Edges streamed from bpk (coalesced),
// P[src] rows gathered 16-lanes/edge, accumulated into LDS via ds_add_f32.
// H[n] = relu( mean_{s in in(n)} P[s] + bias + R[n] );  R may alias H.

__global__ __launch_bounds__(256) void agg_bucket_kernel(
        const unsigned short* __restrict__ P, const float* __restrict__ R,
        const float* __restrict__ bias,
        const unsigned int* __restrict__ bpk, const int* __restrict__ bofs,
        float* __restrict__ H, int N) {
    __shared__ float acc[BVALS * ASTRIDE];   // 17.4KB, row-skewed vs 32 banks
    __shared__ int dcnt[BVALS];
    int b = blockIdx.x;
    int t = threadIdx.x;
    for (int i = t; i < BVALS * ASTRIDE; i += 256) acc[i] = 0.f;
    if (t < BVALS) dcnt[t] = 0;
    __syncthreads();

    int e0 = bofs[b], e1 = bofs[b + 1];
    int l = t & 15;
    for (int i = e0 + (t >> 4); i < e1; i += 16) {
        unsigned v = bpk[i];
        int src = v & 0xFFFF;
        int dl = (v >> 16) & 63;
        ushort4 u = *(const ushort4*)&P[(size_t)src * 64 + l * 4];
        float* a = &acc[dl * ASTRIDE + l * 4];
        atomicAdd(&a[0], bf2f(u.x));
        atomicAdd(&a[1], bf2f(u.y));
        atomicAdd(&a[2], bf2f(u.z));
        atomicAdd(&a[3], bf2f(u.w));
        if (l == 0) atomicAdd(&dcnt[dl], 1);
    }
    __syncthreads();

    // epilogue: 64 nodes x 4 lanes, each lane 16 consecutive floats
    int nl = t >> 2;
    int n = b * BVALS + nl;
    if (n >= N) return;
    int q = (t & 3) * 16;
    float inv = 1.0f / fmaxf((float)dcnt[nl], 1.0f);
#pragma unroll
    for (int j = 0; j < 16; j += 4) {
        int f = q + j;
        float4 s = *(float4*)&acc[nl * ASTRIDE + f];
        float4 bb = *(const float4*)&bias[f];
        float4 rr = *(const float4*)&R[(size_t)n * 64 + f];
        float4 h;
        h.x = fmaxf(fmaf(s.x, inv, bb.x + rr.x), 0.f);
        h.y = fmaxf(fmaf(s.y, inv, bb.y + rr.y), 0.f);
        h.z = fmaxf(fmaf(s.z, inv, bb.z + rr.z), 0.f);
        h.w = fmaxf(fmaf(s.w, inv, bb.w + rr.w), 0.f);
        *(float4*)&H[(size_t)n * 64 + f] = h;
    }
}

// ---------------- edge output: out[e] = relu(Pa[src] + Pb[dst] + bm1) @ Wm2 + bm2 ----

__global__ __launch_bounds__(256) void edge_out_kernel(
        const unsigned short* __restrict__ Pa, const unsigned short* __restrict__ Pb,
        const int* __restrict__ ei,
        const float* __restrict__ bm1,
        const float* __restrict__ Wm2, const float* __restrict__ bm2,
        float* __restrict__ out, int E) {
    int t = threadIdx.x;
    int l = t & 15;
    int eg = t >> 4;
    int base = blockIdx.x * 64 + eg;

    float4 bb  = *(const float4*)&bm1[l * 4];
    float4 w01 = *(const float4*)&Wm2[l * 8];
    float4 w23 = *(const float4*)&Wm2[l * 8 + 4];
    float ob0 = bm2[0], ob1 = bm2[1];

#pragma unroll
    for (int it = 0; it < 4; ++it) {
        int e = base + it * 16;
        int s = ei[e];
        int d = ei[E + e];
        ushort4 ua = *(const ushort4*)&Pa[(size_t)s * 64 + l * 4];
        ushort4 ub = *(const ushort4*)&Pb[(size_t)d * 64 + l * 4];
        float h0 = fmaxf(bf2f(ua.x) + bf2f(ub.x) + bb.x, 0.f);
        float h1 = fmaxf(bf2f(ua.y) + bf2f(ub.y) + bb.y, 0.f);
        float h2 = fmaxf(bf2f(ua.z) + bf2f(ub.z) + bb.z, 0.f);
        float h3 = fmaxf(bf2f(ua.w) + bf2f(ub.w) + bb.w, 0.f);
        float s0 = h0 * w01.x + h1 * w01.z + h2 * w23.x + h3 * w23.z;
        float s1 = h0 * w01.y + h1 * w01.w + h2 * w23.y + h3 * w23.w;
#pragma unroll
        for (int off = 8; off >= 1; off >>= 1) {
            s0 += __shfl_xor(s0, off, 64);
            s1 += __shfl_xor(s1, off, 64);
        }
        if (l == 0) {
            *(float2*)&out[(size_t)e * 2] = make_float2(s0 + ob0, s1 + ob1);
        }
    }
}

// ---------------- launch ----------------

extern "C" void kernel_launch(void* const* d_in, const int* in_sizes, int n_in,
                              void* d_out, int out_size, void* d_ws, size_t ws_size,
                              hipStream_t stream) {
    const float* x   = (const float*)d_in[0];
    const int*   ei  = (const int*)d_in[1];
    const float* W1l = (const float*)d_in[2];
    const float* b1l = (const float*)d_in[3];
    const float* W1r = (const float*)d_in[4];
    const float* W2l = (const float*)d_in[5];
    const float* b2l = (const float*)d_in[6];
    const float* W2r = (const float*)d_in[7];
    const float* Wm1 = (const float*)d_in[8];
    const float* bm1 = (const float*)d_in[9];
    const float* Wm2 = (const float*)d_in[10];
    const float* bm2 = (const float*)d_in[11];
    float* out = (float*)d_out;

    const int N = N_NODES, E = N_EDGES;
    const int NSB = (E + CHUNK - 1) / CHUNK;   // 196 count/scatter blocks

    float* B0 = (float*)d_ws;                        // 12.8 MB: xl -> p2l -> Pa (bf16)
    float* B1 = B0 + (size_t)N * 64;                 // 12.8 MB: p1r/h1 (fp32) -> Pb (bf16)
    float* B2 = B1 + (size_t)N * 64;                 // 12.8 MB: p2r/h2 (fp32)
    unsigned int* bpk = (unsigned int*)(B2 + (size_t)N * 64);   // [E] 3.2 MB
    int* bofs     = (int*)(bpk + E);                 // [NBUK+1]
    int* bcnt_pad = bofs + NBUK + 1;                 // [NBUK*PAD] 50KB
    int* gcur_pad = bcnt_pad + NBUK * PAD;           // [NBUK*PAD] 50KB

    unsigned short* B0h = (unsigned short*)B0;
    unsigned short* B1h = (unsigned short*)B1;

    hipMemsetAsync(bcnt_pad, 0, sizeof(int) * NBUK * PAD, stream);

    // bucket build
    count_kernel<<<NSB, 256, 0, stream>>>(ei, bcnt_pad, E);
    scan_kernel<<<1, 1024, 0, stream>>>(bcnt_pad, bofs, gcur_pad);
    scatter_kernel<<<NSB, 256, 0, stream>>>(ei, gcur_pad, bpk, E);

    // conv1: xl = x@W1l (B0, bf16), p1r = x@W1r (B1, fp32)
    gemm_dual_kernel<128><<<(N + 31) / 32, 256, 0, stream>>>(x, W1l, W1r, B0h, B1, N);
    // h1 = relu(mean(xl[src]) + b1l + p1r) -> B1 (fp32)
    agg_bucket_kernel<<<NBUK, 256, 0, stream>>>(B0h, B1, b1l, bpk, bofs, B1, N);

    // conv2: p2l = h1@W2l (B0, bf16), p2r = h1@W2r (B2, fp32)
    gemm_dual_kernel<64><<<(N + 31) / 32, 256, 0, stream>>>(B1, W2l, W2r, B0h, B2, N);
    // h2 = relu(mean(p2l[src]) + b2l + p2r) -> B2 (fp32)
    agg_bucket_kernel<<<NBUK, 256, 0, stream>>>(B0h, B2, b2l, bpk, bofs, B2, N);

    // edge-MLP first layer, per-node halves: Pa = h2@Wm1_top (bf16), Pb = h2@Wm1_bot (bf16)
    gemm_dual_kernel<64><<<(N + 31) / 32, 256, 0, stream>>>(B2, Wm1, Wm1 + 64 * 64, B0h, B1h, N);

    // per-edge: out = relu(Pa[src] + Pb[dst] + bm1) @ Wm2 + bm2
    edge_out_kernel<<<E / 64, 256, 0, stream>>>(B0h, B1h, ei, bm1, Wm2, bm2, out, E);
}

// Round 8
// 203.884 us; speedup vs baseline: 4.1155x; 4.1155x over previous
//
#include <hip/hip_runtime.h>

#define N_NODES 50000
#define N_EDGES 800000

#define BVALS 64                                  // nodes per bucket
#define NBUK ((N_NODES + BVALS - 1) / BVALS)      // 782
#define PAD 16                                    // ints per padded counter (64B line)
#define CHUNK 4096                                // edges per count/scatter block
#define BCAP 2048                                 // LDS capacity per bucket sort

// ---------------- bf16 helpers (tables stored bf16, math in fp32) ----------------

__device__ __forceinline__ float bf2f(unsigned short u) {
    return __uint_as_float(((unsigned)u) << 16);
}
__device__ __forceinline__ unsigned short f2bf(float f) {
    unsigned u = __float_as_uint(f);
    u += 0x7FFFu + ((u >> 16) & 1u);   // round-to-nearest-even
    return (unsigned short)(u >> 16);
}
__device__ __forceinline__ void stv(float* p, float v) { *p = v; }
__device__ __forceinline__ void stv(unsigned short* p, float v) { *p = f2bf(v); }

// ---------------- bucket build: count -> scan -> scatter -> per-bucket sort ------
// Contention control: per-block LDS histograms (int atomics only); global
// counters padded one per 64B line.

__global__ __launch_bounds__(256) void count_kernel(
        const int* __restrict__ ei, int* __restrict__ bcnt_pad, int E) {
    __shared__ int hist[NBUK];
    int t = threadIdx.x;
    for (int h = t; h < NBUK; h += 256) hist[h] = 0;
    __syncthreads();
    int e0 = blockIdx.x * CHUNK;
    int ne = min(CHUNK, E - e0);
    for (int i = t; i < ne; i += 256)
        atomicAdd(&hist[ei[E + e0 + i] >> 6], 1);
    __syncthreads();
    for (int h = t; h < NBUK; h += 256) {
        int c = hist[h];
        if (c) atomicAdd(&bcnt_pad[h * PAD], c);
    }
}

__global__ __launch_bounds__(1024) void scan_bcnt_kernel(
        const int* __restrict__ bcnt_pad, int* __restrict__ bofs,
        int* __restrict__ gcur_pad) {
    __shared__ int lds[1024];
    int t = threadIdx.x;
    int v = (t < NBUK) ? bcnt_pad[t * PAD] : 0;
    lds[t] = v;
    __syncthreads();
    for (int off = 1; off < 1024; off <<= 1) {
        int u = (t >= off) ? lds[t - off] : 0;
        __syncthreads();
        lds[t] += u;
        __syncthreads();
    }
    if (t <= NBUK) bofs[t] = lds[t] - v;          // exclusive; bofs[NBUK] = E
    if (t < NBUK) gcur_pad[t * PAD] = lds[t] - v; // scatter cursors start at bofs
}

__global__ __launch_bounds__(256) void scatter_kernel(
        const int* __restrict__ ei, int* __restrict__ gcur_pad,
        unsigned int* __restrict__ bpk, int E) {
    __shared__ unsigned int pk[CHUNK];   // 16KB
    __shared__ int hist[NBUK];           // 3.1KB
    __shared__ int lbase[NBUK];          // 3.1KB
    int t = threadIdx.x;
    for (int h = t; h < NBUK; h += 256) hist[h] = 0;
    __syncthreads();
    int e0 = blockIdx.x * CHUNK;
    int ne = min(CHUNK, E - e0);
    for (int i = t; i < ne; i += 256) {
        unsigned s = (unsigned)ei[e0 + i];
        unsigned d = (unsigned)ei[E + e0 + i];
        pk[i] = (d << 16) | s;
        atomicAdd(&hist[d >> 6], 1);
    }
    __syncthreads();
    for (int h = t; h < NBUK; h += 256) {
        int c = hist[h];
        lbase[h] = c ? atomicAdd(&gcur_pad[h * PAD], c) : 0;
        hist[h] = 0;                     // reuse as local cursor
    }
    __syncthreads();
    for (int i = t; i < ne; i += 256) {
        unsigned v = pk[i];
        int h = (v >> 16) >> 6;
        int idx = atomicAdd(&hist[h], 1);
        bpk[lbase[h] + idx] = v;
    }
}

// per-bucket counting sort (int LDS atomics): emits rowptr + dst-sorted elist.

__global__ __launch_bounds__(256) void bucket_sort_kernel(
        const unsigned int* __restrict__ bpk, const int* __restrict__ bofs,
        int* __restrict__ rowptr, int* __restrict__ elist, int N) {
    __shared__ unsigned int pk[BCAP];   // 8KB
    __shared__ int sc[BVALS];
    __shared__ int cur[BVALS];
    int b = blockIdx.x;
    int t = threadIdx.x;
    int e0 = bofs[b];
    int nb = min(bofs[b + 1] - e0, BCAP);

    if (t < BVALS) sc[t] = 0;
    __syncthreads();
    for (int i = t; i < nb; i += 256) {
        unsigned v = bpk[e0 + i];
        pk[i] = v;
        atomicAdd(&sc[(v >> 16) & 63], 1);
    }
    __syncthreads();
    int hv = (t < BVALS) ? sc[t] : 0;
#pragma unroll
    for (int off = 1; off < BVALS; off <<= 1) {
        int u = (t < BVALS && t >= off) ? sc[t - off] : 0;
        __syncthreads();
        if (t < BVALS) sc[t] += u;
        __syncthreads();
    }
    if (t < BVALS) {
        int ex = sc[t] - hv;             // exclusive prefix within bucket
        cur[t] = ex;
        int n = b * BVALS + t;
        if (n <= N) rowptr[n] = e0 + ex; // last bucket's tail covers rowptr[N]=E
    }
    __syncthreads();
    for (int i = t; i < nb; i += 256) {
        unsigned v = pk[i];
        int pos = atomicAdd(&cur[(v >> 16) & 63], 1);
        elist[e0 + pos] = v & 0xFFFF;    // src (fits in 16 bits)
    }
}

// ---------------- fused dual GEMM: C0 = A@W0, C1 = A@W1 ----------------

template<int K, typename T0, typename T1>
__global__ __launch_bounds__(256) void gemm_dual_kernel(
        const float* __restrict__ A,
        const float* __restrict__ W0, const float* __restrict__ W1,
        T0* __restrict__ C0, T1* __restrict__ C1, int N) {
    __shared__ float a_lds[32 * K];
    int t = threadIdx.x;
    int n0 = blockIdx.x * 32;

    const int total4 = 32 * K / 4;
    for (int idx = t; idx < total4; idx += 256) {
        int f = idx * 4;
        int r = f / K, c = f % K;
        float4 v = make_float4(0.f, 0.f, 0.f, 0.f);
        if (n0 + r < N) v = *(const float4*)&A[(size_t)(n0 + r) * K + c];
        *(float4*)&a_lds[f] = v;
    }
    __syncthreads();

    int o = t & 63;
    int g = t >> 6;
    float acc0[8], acc1[8];
#pragma unroll
    for (int i = 0; i < 8; ++i) { acc0[i] = 0.f; acc1[i] = 0.f; }

#pragma unroll 2
    for (int k4 = 0; k4 < K; k4 += 4) {
        float w00 = W0[(k4 + 0) * 64 + o];
        float w01 = W0[(k4 + 1) * 64 + o];
        float w02 = W0[(k4 + 2) * 64 + o];
        float w03 = W0[(k4 + 3) * 64 + o];
        float w10 = W1[(k4 + 0) * 64 + o];
        float w11 = W1[(k4 + 1) * 64 + o];
        float w12 = W1[(k4 + 2) * 64 + o];
        float w13 = W1[(k4 + 3) * 64 + o];
#pragma unroll
        for (int i = 0; i < 8; ++i) {
            float4 a = *(const float4*)&a_lds[(g * 8 + i) * K + k4];
            acc0[i] = fmaf(a.x, w00, acc0[i]);
            acc0[i] = fmaf(a.y, w01, acc0[i]);
            acc0[i] = fmaf(a.z, w02, acc0[i]);
            acc0[i] = fmaf(a.w, w03, acc0[i]);
            acc1[i] = fmaf(a.x, w10, acc1[i]);
            acc1[i] = fmaf(a.y, w11, acc1[i]);
            acc1[i] = fmaf(a.z, w12, acc1[i]);
            acc1[i] = fmaf(a.w, w13, acc1[i]);
        }
    }
#pragma unroll
    for (int i = 0; i < 8; ++i) {
        int n = n0 + g * 8 + i;
        if (n < N) {
            stv(&C0[(size_t)n * 64 + o], acc0[i]);
            stv(&C1[(size_t)n * 64 + o], acc1[i]);
        }
    }
}

// ---------------- mean-aggregate + bias + residual + relu (CSR gather) ----------
// H[n] = relu( mean_{s in in(n)} P[s] + bias + R[n] );  P is a bf16 table.
// 16 lanes per node: one wave instruction reads a full 128B row, coalesced.

__global__ __launch_bounds__(256) void agg_relu_kernel(
        const unsigned short* __restrict__ P, const float* __restrict__ R,
        const float* __restrict__ bias,
        const int* __restrict__ rowptr, const int* __restrict__ elist,
        float* __restrict__ H, int N) {
    int t = threadIdx.x;
    int n = blockIdx.x * 16 + (t >> 4);
    int l = t & 15;
    if (n >= N) return;
    int r0 = rowptr[n], r1 = rowptr[n + 1];
    float4 a0 = make_float4(0.f, 0.f, 0.f, 0.f);
    float4 a1 = make_float4(0.f, 0.f, 0.f, 0.f);
    int p = r0;
    for (; p + 2 <= r1; p += 2) {
        int sA = elist[p];
        int sB = elist[p + 1];
        ushort4 v0 = *(const ushort4*)&P[(size_t)sA * 64 + l * 4];
        ushort4 v1 = *(const ushort4*)&P[(size_t)sB * 64 + l * 4];
        a0.x += bf2f(v0.x); a0.y += bf2f(v0.y); a0.z += bf2f(v0.z); a0.w += bf2f(v0.w);
        a1.x += bf2f(v1.x); a1.y += bf2f(v1.y); a1.z += bf2f(v1.z); a1.w += bf2f(v1.w);
    }
    if (p < r1) {
        int sA = elist[p];
        ushort4 v0 = *(const ushort4*)&P[(size_t)sA * 64 + l * 4];
        a0.x += bf2f(v0.x); a0.y += bf2f(v0.y); a0.z += bf2f(v0.z); a0.w += bf2f(v0.w);
    }
    a0.x += a1.x; a0.y += a1.y; a0.z += a1.z; a0.w += a1.w;
    float inv = 1.0f / fmaxf((float)(r1 - r0), 1.0f);
    float4 b = *(const float4*)&bias[l * 4];
    float4 rr = *(const float4*)&R[(size_t)n * 64 + l * 4];
    float4 h;
    h.x = fmaxf(fmaf(a0.x, inv, b.x + rr.x), 0.f);
    h.y = fmaxf(fmaf(a0.y, inv, b.y + rr.y), 0.f);
    h.z = fmaxf(fmaf(a0.z, inv, b.z + rr.z), 0.f);
    h.w = fmaxf(fmaf(a0.w, inv, b.w + rr.w), 0.f);
    *(float4*)&H[(size_t)n * 64 + l * 4] = h;
}

// ---------------- edge output: out[e] = relu(Pa[src] + Pb[dst] + bm1) @ Wm2 + bm2 ----

__global__ __launch_bounds__(256) void edge_out_kernel(
        const unsigned short* __restrict__ Pa, const unsigned short* __restrict__ Pb,
        const int* __restrict__ ei,
        const float* __restrict__ bm1,
        const float* __restrict__ Wm2, const float* __restrict__ bm2,
        float* __restrict__ out, int E) {
    int t = threadIdx.x;
    int l = t & 15;
    int eg = t >> 4;
    int base = blockIdx.x * 64 + eg;

    float4 bb  = *(const float4*)&bm1[l * 4];
    float4 w01 = *(const float4*)&Wm2[l * 8];
    float4 w23 = *(const float4*)&Wm2[l * 8 + 4];
    float ob0 = bm2[0], ob1 = bm2[1];

#pragma unroll
    for (int it = 0; it < 4; ++it) {
        int e = base + it * 16;
        int s = ei[e];
        int d = ei[E + e];
        ushort4 ua = *(const ushort4*)&Pa[(size_t)s * 64 + l * 4];
        ushort4 ub = *(const ushort4*)&Pb[(size_t)d * 64 + l * 4];
        float h0 = fmaxf(bf2f(ua.x) + bf2f(ub.x) + bb.x, 0.f);
        float h1 = fmaxf(bf2f(ua.y) + bf2f(ub.y) + bb.y, 0.f);
        float h2 = fmaxf(bf2f(ua.z) + bf2f(ub.z) + bb.z, 0.f);
        float h3 = fmaxf(bf2f(ua.w) + bf2f(ub.w) + bb.w, 0.f);
        float s0 = h0 * w01.x + h1 * w01.z + h2 * w23.x + h3 * w23.z;
        float s1 = h0 * w01.y + h1 * w01.w + h2 * w23.y + h3 * w23.w;
#pragma unroll
        for (int off = 8; off >= 1; off >>= 1) {
            s0 += __shfl_xor(s0, off, 64);
            s1 += __shfl_xor(s1, off, 64);
        }
        if (l == 0) {
            *(float2*)&out[(size_t)e * 2] = make_float2(s0 + ob0, s1 + ob1);
        }
    }
}

// ---------------- launch ----------------

extern "C" void kernel_launch(void* const* d_in, const int* in_sizes, int n_in,
                              void* d_out, int out_size, void* d_ws, size_t ws_size,
                              hipStream_t stream) {
    const float* x   = (const float*)d_in[0];
    const int*   ei  = (const int*)d_in[1];
    const float* W1l = (const float*)d_in[2];
    const float* b1l = (const float*)d_in[3];
    const float* W1r = (const float*)d_in[4];
    const float* W2l = (const float*)d_in[5];
    const float* b2l = (const float*)d_in[6];
    const float* W2r = (const float*)d_in[7];
    const float* Wm1 = (const float*)d_in[8];
    const float* bm1 = (const float*)d_in[9];
    const float* Wm2 = (const float*)d_in[10];
    const float* bm2 = (const float*)d_in[11];
    float* out = (float*)d_out;

    const int N = N_NODES, E = N_EDGES;
    const int NSB = (E + CHUNK - 1) / CHUNK;   // 196 count/scatter blocks

    float* B0 = (float*)d_ws;                        // 12.8 MB: xl -> p2l -> Pa (bf16)
    float* B1 = B0 + (size_t)N * 64;                 // 12.8 MB: p1r/h1 (fp32) -> Pb (bf16)
    float* B2 = B1 + (size_t)N * 64;                 // 12.8 MB: p2r/h2 (fp32)
    int* rowptr   = (int*)(B2 + (size_t)N * 64);     // [N+1]
    int* elist    = rowptr + N + 1;                  // [E] 3.2 MB
    int* bofs     = elist + E;                       // [NBUK+1]
    int* bcnt_pad = bofs + NBUK + 1;                 // [NBUK*PAD] 50KB
    int* gcur_pad = bcnt_pad + NBUK * PAD;           // [NBUK*PAD] 50KB
    // bpk aliases B2: consumed by bucket_sort before conv2's GEMM writes B2.
    unsigned int* bpk = (unsigned int*)B2;           // [E] 3.2 MB <= 12.8 MB slot

    unsigned short* B0h = (unsigned short*)B0;
    unsigned short* B1h = (unsigned short*)B1;

    hipMemsetAsync(bcnt_pad, 0, sizeof(int) * NBUK * PAD, stream);

    // CSR build: count -> scan -> bucket scatter -> per-bucket counting sort
    count_kernel<<<NSB, 256, 0, stream>>>(ei, bcnt_pad, E);
    scan_bcnt_kernel<<<1, 1024, 0, stream>>>(bcnt_pad, bofs, gcur_pad);
    scatter_kernel<<<NSB, 256, 0, stream>>>(ei, gcur_pad, bpk, E);
    bucket_sort_kernel<<<NBUK, 256, 0, stream>>>(bpk, bofs, rowptr, elist, N);

    // conv1: xl = x@W1l (B0, bf16), p1r = x@W1r (B1, fp32)
    gemm_dual_kernel<128><<<(N + 31) / 32, 256, 0, stream>>>(x, W1l, W1r, B0h, B1, N);
    // h1 = relu(mean(xl[src]) + b1l + p1r) -> B1 (fp32)
    agg_relu_kernel<<<(N + 15) / 16, 256, 0, stream>>>(B0h, B1, b1l, rowptr, elist, B1, N);

    // conv2: p2l = h1@W2l (B0, bf16), p2r = h1@W2r (B2, fp32)
    gemm_dual_kernel<64><<<(N + 31) / 32, 256, 0, stream>>>(B1, W2l, W2r, B0h, B2, N);
    // h2 = relu(mean(p2l[src]) + b2l + p2r) -> B2 (fp32)
    agg_relu_kernel<<<(N + 15) / 16, 256, 0, stream>>>(B0h, B2, b2l, rowptr, elist, B2, N);

    // edge-MLP first layer, per-node halves: Pa = h2@Wm1_top (bf16), Pb = h2@Wm1_bot (bf16)
    gemm_dual_kernel<64><<<(N + 31) / 32, 256, 0, stream>>>(B2, Wm1, Wm1 + 64 * 64, B0h, B1h, N);

    // per-edge: out = relu(Pa[src] + Pb[dst] + bm1) @ Wm2 + bm2
    edge_out_kernel<<<E / 64, 256, 0, stream>>>(B0h, B1h, ei, bm1, Wm2, bm2, out, E);
}